// Round 5
// baseline (1139.984 us; speedup 1.0000x reference)
//
#include <hip/hip_runtime.h>
#include <math.h>

#define Nn 65536

typedef short s16x8 __attribute__((ext_vector_type(8)));
typedef float f32x4 __attribute__((ext_vector_type(4)));
typedef unsigned int u32;

__device__ __forceinline__ unsigned short f2bf(float x) {
    u32 u = __float_as_uint(x);
    u += 0x7FFFu + ((u >> 16) & 1u);
    return (unsigned short)(u >> 16);
}

// argmax over row s of the 4x4 type_matching (first max wins, matches jnp.argmax)
__device__ __forceinline__ int best_t_for(const float* __restrict__ tm, int s, float* mOut) {
    float m = tm[s * 4];
    int am = 0;
#pragma unroll
    for (int j = 1; j < 4; ++j) {
        float v = tm[s * 4 + j];
        if (v > m) { m = v; am = j; }
    }
    if (mOut) *mOut = m;
    return am;
}

// ============ k_convert: fp32 [D][H] -> bf16 fragment-linear, 12 live matrices ============
__global__ void k_convert(const float* __restrict__ W1, const float* __restrict__ W2,
                          const float* __restrict__ C1, const float* __restrict__ tm,
                          unsigned short* __restrict__ wbf) {
    int u = blockIdx.x * 256 + threadIdx.x;      // 0..24575; mat = s*3+w, 2048 units each
    int mat = u >> 11;
    int rr = u & 2047;
    int f = rr >> 6, lane = rr & 63;
    int kk = f >> 3, n8 = f & 7;
    int q = lane >> 4, l15 = lane & 15;
    int sm = mat / 3, w = mat - sm * 3;
    int t = best_t_for(tm, sm, nullptr);
    const float* src = (w == 0) ? W1 : (w == 1) ? W2 : C1;
    const float* sp = src + (((sm * 4 + t) << 14) + n8 * 16 + l15);
    int k0 = kk * 32 + q * 8;
    s16x8 o;
#pragma unroll
    for (int j = 0; j < 8; ++j) o[j] = (short)f2bf(sp[(k0 + j) * 128]);
    *(s16x8*)(wbf + (size_t)u * 8) = o;
}

// ============ k_main: 128 consecutive rows/block, in-LDS type sort, reg-held weights ============
// A layout: slot*128 + ((col + (slot&15)*8) & 127)  -- swizzled, conflict-free b128 frags
__global__ __launch_bounds__(256, 2) void k_main(
    const float* __restrict__ states, const float* __restrict__ scores,
    const int* __restrict__ type_ids, const float* __restrict__ tm,
    const float* __restrict__ b1g, const float* __restrict__ b2g, const float* __restrict__ c1g,
    const float* __restrict__ C2, const float* __restrict__ c2,
    const unsigned short* __restrict__ wbf,
    float* __restrict__ out_state, float* __restrict__ out_score, float* __restrict__ out_prob)
{
    __shared__ __align__(16) unsigned short Abuf[192 * 128];  // 48 KB (max padded slots = 173)
    __shared__ __align__(16) unsigned short Hbuf[64 * 128];   // 16 KB
    __shared__ int sortSlot[192];     // -> local row (0..127) or -1 (pad)
    __shared__ float scoreLds[192];
    __shared__ float pLds[4][64];
    __shared__ float C2s[128];
    __shared__ int cnt4[4];

    const int t = threadIdx.x;
    const int base = blockIdx.x * 128;
    const int lane = t & 63;
    const int wv = t >> 6;            // wave -> 32-col slice (n-groups 2wv, 2wv+1)
    const int l15 = lane & 15;
    const int quad = lane >> 4;

    if (t < 4) cnt4[t] = 0;
    if (t < 192) sortSlot[t] = -1;
    __syncthreads();

    // ---- count types (rank = atomic return) + item_prob ----
    int myType = 0, myPos = 0;
    if (t < 128) {
        myType = type_ids[base + t];
        myPos = atomicAdd(&cnt4[myType], 1);
        float m;
        best_t_for(tm, myType, &m);
        out_prob[base + t] = 1.f / (1.f + expf(-m));
    }
    __syncthreads();

    // ---- padded segment starts (uniform) + scatter ranks into sortSlot ----
    int cntR[4], starts[4];
    {
        int acc = 0;
#pragma unroll
        for (int s = 0; s < 4; ++s) {
            cntR[s] = cnt4[s];
            starts[s] = acc;
            acc += (cntR[s] + 15) & ~15;
        }
    }
    if (t < 128) sortSlot[starts[myType] + myPos] = t;
    __syncthreads();

    // ---- stage A (type-sorted, swizzled, fp32->bf16) + per-slot score ----
    for (int j = t >> 1; j < 192; j += 128) {
        const int h = t & 1;
        const int row = sortSlot[j];
        const int rot = (j & 15) << 3;
        unsigned short* dstRow = &Abuf[j * 128];
        if (row >= 0) {
            if (h == 0) scoreLds[j] = scores[base + row];
            const float4* sp = (const float4*)(states + (size_t)(base + row) * 128 + h * 64);
#pragma unroll
            for (int half = 0; half < 2; ++half) {
                float4 v[8];
#pragma unroll
                for (int i = 0; i < 8; ++i) v[i] = sp[half * 8 + i];
#pragma unroll
                for (int i = 0; i < 8; ++i) {
                    int col = (h * 64 + half * 32 + i * 4 + rot) & 127;
                    ushort4 o;
                    o.x = f2bf(v[i].x); o.y = f2bf(v[i].y);
                    o.z = f2bf(v[i].z); o.w = f2bf(v[i].w);
                    *(ushort4*)(dstRow + col) = o;
                }
            }
        } else {
            if (h == 0) scoreLds[j] = 0.f;
#pragma unroll
            for (int i = 0; i < 16; ++i) {
                int col = (h * 64 + i * 4 + rot) & 127;
                *(ushort4*)(dstRow + col) = ushort4{0, 0, 0, 0};
            }
        }
    }
    __syncthreads();

    // ---- per-type phases ----
    for (int s = 0; s < 4; ++s) {
        const int paddedCnt = (cntR[s] + 15) & ~15;
        const int stIdx = s * 4 + best_t_for(tm, s, nullptr);

        // weights for this wave's col-slice -> registers (bf16 frag-linear, L2-hit)
        s16x8 wf[3][4][2];
        {
            const unsigned short* wb = wbf + (size_t)s * 3 * 16384;
#pragma unroll
            for (int m = 0; m < 3; ++m)
#pragma unroll
                for (int kk = 0; kk < 4; ++kk)
#pragma unroll
                    for (int nn = 0; nn < 2; ++nn)
                        wf[m][kk][nn] = *(const s16x8*)(wb + m * 16384 +
                            (size_t)((kk * 8 + (wv * 2 + nn)) * 64 + lane) * 8);
        }
        float b1v[2], b2v[2], c1v[2];
#pragma unroll
        for (int nn = 0; nn < 2; ++nn) {
            int col = (wv * 2 + nn) * 16 + l15;
            b1v[nn] = b1g[stIdx * 128 + col];
            b2v[nn] = b2g[stIdx * 128 + col];
            c1v[nn] = c1g[stIdx * 128 + col];
        }
        const float c2s = c2[stIdx];
        if (t < 128) C2s[t] = C2[stIdx * 128 + t];   // ordered vs prev gemm3 by prev b2

        auto gemm = [&](const unsigned short* Ab, int wm, int mgc, f32x4 acc[4][2]) {
#pragma unroll
            for (int mg = 0; mg < 4; ++mg)
#pragma unroll
                for (int nn = 0; nn < 2; ++nn) acc[mg][nn] = f32x4{0.f, 0.f, 0.f, 0.f};
#pragma unroll
            for (int kk = 0; kk < 4; ++kk) {
                const int colsw = (kk * 32 + quad * 8 + l15 * 8) & 127;
                s16x8 af[4];
                for (int mg = 0; mg < mgc; ++mg)
                    af[mg] = *(const s16x8*)(Ab + (mg * 16 + l15) * 128 + colsw);
                for (int mg = 0; mg < mgc; ++mg)
#pragma unroll
                    for (int nn = 0; nn < 2; ++nn)
                        acc[mg][nn] = __builtin_amdgcn_mfma_f32_16x16x32_bf16(
                            af[mg], wf[wm][kk][nn], acc[mg][nn], 0, 0, 0);
            }
        };

        for (int cb = 0; cb < paddedCnt; cb += 64) {
            const int slotBase = starts[s] + cb;
            const int mgc = ((paddedCnt - cb < 64) ? (paddedCnt - cb) : 64) >> 4;
            f32x4 acc[4][2];

            // ---- phase 1: h = relu(A@W1 + b1) -> Hbuf (swizzled, chunk-local rows) ----
            gemm(Abuf + (size_t)slotBase * 128, 0, mgc, acc);
            for (int mg = 0; mg < mgc; ++mg)
#pragma unroll
                for (int nn = 0; nn < 2; ++nn) {
                    int col = (wv * 2 + nn) * 16 + l15;
#pragma unroll
                    for (int r = 0; r < 4; ++r) {
                        int lr = mg * 16 + quad * 4 + r;
                        float v = fmaxf(acc[mg][nn][r] + b1v[nn], 0.f);
                        Hbuf[lr * 128 + ((col + ((lr & 15) << 3)) & 127)] = f2bf(v);
                    }
                }
            __syncthreads();   // b1: H ready

            // ---- phase 2: y = h@W2 + b2 -> out_state (block-local rows) ----
            gemm(Hbuf, 1, mgc, acc);
            for (int mg = 0; mg < mgc; ++mg) {
                int lr4[4];
#pragma unroll
                for (int r = 0; r < 4; ++r)
                    lr4[r] = sortSlot[slotBase + mg * 16 + quad * 4 + r];
#pragma unroll
                for (int nn = 0; nn < 2; ++nn) {
                    int col = (wv * 2 + nn) * 16 + l15;
                    float bias = b2v[nn];
#pragma unroll
                    for (int r = 0; r < 4; ++r)
                        if (lr4[r] >= 0)
                            out_state[(size_t)(base + lr4[r]) * 128 + col] = acc[mg][nn][r] + bias;
                }
            }

            // ---- phase 3: classifier partials (this wave's 32 cols) ----
            gemm(Abuf + (size_t)slotBase * 128, 2, mgc, acc);
            {
                float part[4][4];
#pragma unroll
                for (int mg = 0; mg < 4; ++mg)
#pragma unroll
                    for (int r = 0; r < 4; ++r) part[mg][r] = 0.f;
#pragma unroll
                for (int nn = 0; nn < 2; ++nn) {
                    int col = (wv * 2 + nn) * 16 + l15;
                    float cw = C2s[col];
                    for (int mg = 0; mg < mgc; ++mg)
#pragma unroll
                        for (int r = 0; r < 4; ++r)
                            part[mg][r] += fmaxf(acc[mg][nn][r] + c1v[nn], 0.f) * cw;
                }
#pragma unroll
                for (int off = 1; off < 16; off <<= 1)
                    for (int mg = 0; mg < mgc; ++mg)
#pragma unroll
                        for (int r = 0; r < 4; ++r)
                            part[mg][r] += __shfl_xor(part[mg][r], off, 64);
                if (l15 == 0)
                    for (int mg = 0; mg < mgc; ++mg)
#pragma unroll
                        for (int r = 0; r < 4; ++r)
                            pLds[wv][mg * 16 + quad * 4 + r] = part[mg][r];
            }
            __syncthreads();   // b2: pLds ready; H/A reads of this chunk done

            // ---- epilogue: cross-wave sum, sigmoid, min, store ----
            if (t < mgc * 16) {
                int sl = slotBase + t;
                int lr = sortSlot[sl];
                if (lr >= 0) {
                    float tot = pLds[0][t] + pLds[1][t] + pLds[2][t] + pLds[3][t] + c2s;
                    float cls = 1.f / (1.f + expf(-tot));
                    out_score[base + lr] = fminf(scoreLds[sl], cls);
                }
            }
        }
    }
}

extern "C" void kernel_launch(void* const* d_in, const int* in_sizes, int n_in,
                              void* d_out, int out_size, void* d_ws, size_t ws_size,
                              hipStream_t stream) {
    const float* states = (const float*)d_in[0];
    const float* scores = (const float*)d_in[1];
    const int*   type_ids = (const int*)d_in[2];
    const float* tm = (const float*)d_in[3];
    const float* W1 = (const float*)d_in[4];
    const float* b1 = (const float*)d_in[5];
    const float* W2 = (const float*)d_in[6];
    const float* b2 = (const float*)d_in[7];
    const float* C1 = (const float*)d_in[8];
    const float* c1 = (const float*)d_in[9];
    const float* C2 = (const float*)d_in[10];
    const float* c2 = (const float*)d_in[11];

    unsigned short* wbf = (unsigned short*)d_ws;            // 12 * 16384 bf16, frag-linear

    float* out_state = (float*)d_out;                       // N*128
    float* out_score = out_state + (size_t)Nn * 128;        // N
    float* out_prob  = out_score + Nn;                      // N

    k_convert<<<96, 256, 0, stream>>>(W1, W2, C1, tm, wbf);
    k_main<<<512, 256, 0, stream>>>(states, scores, type_ids, tm, b1, b2, c1,
        C2, c2, wbf, out_state, out_score, out_prob);
}

// Round 6
// 128.833 us; speedup vs baseline: 8.8486x; 8.8486x over previous
//
#include <hip/hip_runtime.h>
#include <math.h>

#define Nn 65536

typedef short s16x8 __attribute__((ext_vector_type(8)));
typedef float f32x4 __attribute__((ext_vector_type(4)));
typedef unsigned int u32;

__device__ __forceinline__ unsigned short f2bf(float x) {
    u32 u = __float_as_uint(x);
    u += 0x7FFFu + ((u >> 16) & 1u);
    return (unsigned short)(u >> 16);
}

// argmax over row s of the 4x4 type_matching (first max wins, matches jnp.argmax)
__device__ __forceinline__ int best_t_for(const float* __restrict__ tm, int s, float* mOut) {
    float m = tm[s * 4];
    int am = 0;
#pragma unroll
    for (int j = 1; j < 4; ++j) {
        float v = tm[s * 4 + j];
        if (v > m) { m = v; am = j; }
    }
    if (mOut) *mOut = m;
    return am;
}

// ============ k_convert: fp32 [D][H] -> bf16 fragment-linear, 12 live matrices ============
__global__ void k_convert(const float* __restrict__ W1, const float* __restrict__ W2,
                          const float* __restrict__ C1, const float* __restrict__ tm,
                          unsigned short* __restrict__ wbf) {
    int u = blockIdx.x * 256 + threadIdx.x;      // 0..24575; mat = s*3+w, 2048 units each
    int mat = u >> 11;
    int rr = u & 2047;
    int f = rr >> 6, lane = rr & 63;
    int kk = f >> 3, n8 = f & 7;
    int q = lane >> 4, l15 = lane & 15;
    int sm = mat / 3, w = mat - sm * 3;
    int t = best_t_for(tm, sm, nullptr);
    const float* src = (w == 0) ? W1 : (w == 1) ? W2 : C1;
    const float* sp = src + (((sm * 4 + t) << 14) + n8 * 16 + l15);
    int k0 = kk * 32 + q * 8;
    s16x8 o;
#pragma unroll
    for (int j = 0; j < 8; ++j) o[j] = (short)f2bf(sp[(k0 + j) * 128]);
    *(s16x8*)(wbf + (size_t)u * 8) = o;
}

// ============ k_main: 128 consecutive rows/block, in-LDS type sort, reg-held weights ============
// A layout: slot*128 + ((col + (slot&15)*8) & 127)  -- swizzled, conflict-free b128 frags
// NOTE: all register arrays (wf, acc, af) indexed ONLY by compile-time constants;
// tails handled by uniform `if (mg*16 < rem)` predication. Runtime loop bounds here
// previously forced acc/af into scratch -> 25x regression (Round 5).
__global__ __launch_bounds__(256, 2) void k_main(
    const float* __restrict__ states, const float* __restrict__ scores,
    const int* __restrict__ type_ids, const float* __restrict__ tm,
    const float* __restrict__ b1g, const float* __restrict__ b2g, const float* __restrict__ c1g,
    const float* __restrict__ C2, const float* __restrict__ c2,
    const unsigned short* __restrict__ wbf,
    float* __restrict__ out_state, float* __restrict__ out_score, float* __restrict__ out_prob)
{
    __shared__ __align__(16) unsigned short Abuf[192 * 128];  // 48 KB (max padded slots = 173)
    __shared__ __align__(16) unsigned short Hbuf[64 * 128];   // 16 KB
    __shared__ int sortSlot[192];     // -> local row (0..127) or -1 (pad)
    __shared__ float scoreLds[192];
    __shared__ float pLds[4][64];
    __shared__ float C2s[128];
    __shared__ int cnt4[4];

    const int t = threadIdx.x;
    const int base = blockIdx.x * 128;
    const int lane = t & 63;
    const int wv = t >> 6;            // wave -> 32-col slice (n-groups 2wv, 2wv+1)
    const int l15 = lane & 15;
    const int quad = lane >> 4;

    if (t < 4) cnt4[t] = 0;
    if (t < 192) sortSlot[t] = -1;
    __syncthreads();

    // ---- count types (rank = atomic return) + item_prob ----
    int myType = 0, myPos = 0;
    if (t < 128) {
        myType = type_ids[base + t];
        myPos = atomicAdd(&cnt4[myType], 1);
        float m;
        best_t_for(tm, myType, &m);
        out_prob[base + t] = 1.f / (1.f + expf(-m));
    }
    __syncthreads();

    // ---- padded segment starts (uniform) + scatter ranks into sortSlot ----
    int cntR[4], starts[4];
    {
        int acc = 0;
#pragma unroll
        for (int s = 0; s < 4; ++s) {
            cntR[s] = cnt4[s];
            starts[s] = acc;
            acc += (cntR[s] + 15) & ~15;
        }
    }
    if (t < 128) sortSlot[starts[myType] + myPos] = t;
    __syncthreads();

    // ---- stage A (type-sorted, swizzled, fp32->bf16) + per-slot score ----
    for (int j = t >> 1; j < 192; j += 128) {
        const int h = t & 1;
        const int row = sortSlot[j];
        const int rot = (j & 15) << 3;
        unsigned short* dstRow = &Abuf[j * 128];
        if (row >= 0) {
            if (h == 0) scoreLds[j] = scores[base + row];
            const float4* sp = (const float4*)(states + (size_t)(base + row) * 128 + h * 64);
#pragma unroll
            for (int half = 0; half < 2; ++half) {
                float4 v[8];
#pragma unroll
                for (int i = 0; i < 8; ++i) v[i] = sp[half * 8 + i];
#pragma unroll
                for (int i = 0; i < 8; ++i) {
                    int col = (h * 64 + half * 32 + i * 4 + rot) & 127;
                    ushort4 o;
                    o.x = f2bf(v[i].x); o.y = f2bf(v[i].y);
                    o.z = f2bf(v[i].z); o.w = f2bf(v[i].w);
                    *(ushort4*)(dstRow + col) = o;
                }
            }
        } else {
            if (h == 0) scoreLds[j] = 0.f;
#pragma unroll
            for (int i = 0; i < 16; ++i) {
                int col = (h * 64 + i * 4 + rot) & 127;
                *(ushort4*)(dstRow + col) = ushort4{0, 0, 0, 0};
            }
        }
    }
    __syncthreads();

    // ---- per-type phases ----
    for (int s = 0; s < 4; ++s) {
        const int paddedCnt = (cntR[s] + 15) & ~15;
        const int stIdx = s * 4 + best_t_for(tm, s, nullptr);

        // weights for this wave's col-slice -> registers (bf16 frag-linear, L2-hit)
        s16x8 wf[3][4][2];
        {
            const unsigned short* wb = wbf + (size_t)s * 3 * 16384;
#pragma unroll
            for (int m = 0; m < 3; ++m)
#pragma unroll
                for (int kk = 0; kk < 4; ++kk)
#pragma unroll
                    for (int nn = 0; nn < 2; ++nn)
                        wf[m][kk][nn] = *(const s16x8*)(wb + m * 16384 +
                            (size_t)((kk * 8 + (wv * 2 + nn)) * 64 + lane) * 8);
        }
        float b1v[2], b2v[2], c1v[2];
#pragma unroll
        for (int nn = 0; nn < 2; ++nn) {
            int col = (wv * 2 + nn) * 16 + l15;
            b1v[nn] = b1g[stIdx * 128 + col];
            b2v[nn] = b2g[stIdx * 128 + col];
            c1v[nn] = c1g[stIdx * 128 + col];
        }
        const float c2s = c2[stIdx];
        if (t < 128) C2s[t] = C2[stIdx * 128 + t];   // ordered vs prev phase-3 by b2 barrier

        // rem uniform across block; all reg arrays constant-indexed
        auto gemm = [&](const unsigned short* Ab, int wm, int rem, f32x4 acc[4][2]) {
#pragma unroll
            for (int mg = 0; mg < 4; ++mg)
#pragma unroll
                for (int nn = 0; nn < 2; ++nn) acc[mg][nn] = f32x4{0.f, 0.f, 0.f, 0.f};
#pragma unroll
            for (int kk = 0; kk < 4; ++kk) {
                const int colsw = (kk * 32 + quad * 8 + l15 * 8) & 127;
                s16x8 af[4];
#pragma unroll
                for (int mg = 0; mg < 4; ++mg)
                    if (mg * 16 < rem)
                        af[mg] = *(const s16x8*)(Ab + (mg * 16 + l15) * 128 + colsw);
#pragma unroll
                for (int mg = 0; mg < 4; ++mg)
                    if (mg * 16 < rem)
#pragma unroll
                        for (int nn = 0; nn < 2; ++nn)
                            acc[mg][nn] = __builtin_amdgcn_mfma_f32_16x16x32_bf16(
                                af[mg], wf[wm][kk][nn], acc[mg][nn], 0, 0, 0);
            }
        };

        for (int cb = 0; cb < paddedCnt; cb += 64) {
            const int slotBase = starts[s] + cb;
            const int rem = ((paddedCnt - cb < 64) ? (paddedCnt - cb) : 64);  // uniform
            f32x4 acc[4][2];

            // ---- phase 1: h = relu(A@W1 + b1) -> Hbuf (swizzled, chunk-local rows) ----
            gemm(Abuf + (size_t)slotBase * 128, 0, rem, acc);
#pragma unroll
            for (int mg = 0; mg < 4; ++mg)
                if (mg * 16 < rem)
#pragma unroll
                    for (int nn = 0; nn < 2; ++nn) {
                        int col = (wv * 2 + nn) * 16 + l15;
#pragma unroll
                        for (int r = 0; r < 4; ++r) {
                            int lr = mg * 16 + quad * 4 + r;
                            float v = fmaxf(acc[mg][nn][r] + b1v[nn], 0.f);
                            Hbuf[lr * 128 + ((col + ((lr & 15) << 3)) & 127)] = f2bf(v);
                        }
                    }
            __syncthreads();   // b1: H ready

            // ---- phase 2: y = h@W2 + b2 -> out_state (block-local rows) ----
            gemm(Hbuf, 1, rem, acc);
#pragma unroll
            for (int mg = 0; mg < 4; ++mg)
                if (mg * 16 < rem) {
                    int lr4[4];
#pragma unroll
                    for (int r = 0; r < 4; ++r)
                        lr4[r] = sortSlot[slotBase + mg * 16 + quad * 4 + r];
#pragma unroll
                    for (int nn = 0; nn < 2; ++nn) {
                        int col = (wv * 2 + nn) * 16 + l15;
                        float bias = b2v[nn];
#pragma unroll
                        for (int r = 0; r < 4; ++r)
                            if (lr4[r] >= 0)
                                out_state[(size_t)(base + lr4[r]) * 128 + col] =
                                    acc[mg][nn][r] + bias;
                    }
                }

            // ---- phase 3: classifier partials (this wave's 32 cols) ----
            gemm(Abuf + (size_t)slotBase * 128, 2, rem, acc);
            {
                float part[4][4];
#pragma unroll
                for (int mg = 0; mg < 4; ++mg)
#pragma unroll
                    for (int r = 0; r < 4; ++r) part[mg][r] = 0.f;
#pragma unroll
                for (int nn = 0; nn < 2; ++nn) {
                    int col = (wv * 2 + nn) * 16 + l15;
                    float cw = C2s[col];
#pragma unroll
                    for (int mg = 0; mg < 4; ++mg)
                        if (mg * 16 < rem)
#pragma unroll
                            for (int r = 0; r < 4; ++r)
                                part[mg][r] += fmaxf(acc[mg][nn][r] + c1v[nn], 0.f) * cw;
                }
#pragma unroll
                for (int off = 1; off < 16; off <<= 1)
#pragma unroll
                    for (int mg = 0; mg < 4; ++mg)
                        if (mg * 16 < rem)
#pragma unroll
                            for (int r = 0; r < 4; ++r)
                                part[mg][r] += __shfl_xor(part[mg][r], off, 64);
                if (l15 == 0)
#pragma unroll
                    for (int mg = 0; mg < 4; ++mg)
                        if (mg * 16 < rem)
#pragma unroll
                            for (int r = 0; r < 4; ++r)
                                pLds[wv][mg * 16 + quad * 4 + r] = part[mg][r];
            }
            __syncthreads();   // b2: pLds ready; H/A reads of this chunk done

            // ---- epilogue: cross-wave sum, sigmoid, min, store ----
            if (t < rem) {
                int sl = slotBase + t;
                int lr = sortSlot[sl];
                if (lr >= 0) {
                    float tot = pLds[0][t] + pLds[1][t] + pLds[2][t] + pLds[3][t] + c2s;
                    float cls = 1.f / (1.f + expf(-tot));
                    out_score[base + lr] = fminf(scoreLds[sl], cls);
                }
            }
        }
    }
}

extern "C" void kernel_launch(void* const* d_in, const int* in_sizes, int n_in,
                              void* d_out, int out_size, void* d_ws, size_t ws_size,
                              hipStream_t stream) {
    const float* states = (const float*)d_in[0];
    const float* scores = (const float*)d_in[1];
    const int*   type_ids = (const int*)d_in[2];
    const float* tm = (const float*)d_in[3];
    const float* W1 = (const float*)d_in[4];
    const float* b1 = (const float*)d_in[5];
    const float* W2 = (const float*)d_in[6];
    const float* b2 = (const float*)d_in[7];
    const float* C1 = (const float*)d_in[8];
    const float* c1 = (const float*)d_in[9];
    const float* C2 = (const float*)d_in[10];
    const float* c2 = (const float*)d_in[11];

    unsigned short* wbf = (unsigned short*)d_ws;            // 12 * 16384 bf16, frag-linear

    float* out_state = (float*)d_out;                       // N*128
    float* out_score = out_state + (size_t)Nn * 128;        // N
    float* out_prob  = out_score + Nn;                      // N

    k_convert<<<96, 256, 0, stream>>>(W1, W2, C1, tm, wbf);
    k_main<<<512, 256, 0, stream>>>(states, scores, type_ids, tm, b1, b2, c1,
        C2, c2, wbf, out_state, out_score, out_prob);
}